// Round 1
// baseline (220.073 us; speedup 1.0000x reference)
//
#include <hip/hip_runtime.h>
#include <hip/hip_bf16.h>
#include <hip/hip_cooperative_groups.h>

// Problem constants (from reference)
#define BATCH    4096
#define IN_DIM   256
#define OUT_DIM  512
#define KDIM     512       // concat K: [silu(x) | spline(x)]
#define NKNOTS   64
#define NBASIS   60        // NUM_KNOTS - DEGREE - 1

typedef __attribute__((ext_vector_type(8))) short bf16x8;   // 8 bf16 in 4 VGPRs
typedef __attribute__((ext_vector_type(4))) float f32x4;

__device__ __forceinline__ short f2bf(float f) {
    __hip_bfloat16 h = __float2bfloat16(f);
    return *reinterpret_cast<short*>(&h);
}

// ---------------------------------------------------------------------------
// Single fused cooperative kernel. Zero workspace use: the bf16 A (4 MB) and
// Bt (0.5 MB) matrices live inside d_out (8 MB) and are overwritten by C in
// phase 3, after a grid-wide sync guarantees all phase-2 reads completed.
//
// phase 1a: A[b,0:256]=silu(x), A[b,256:512]=spline(x)   (bf16, into d_out)
// phase 1b: Bt[n,k] = bf16(k<256 ? wb[k,n] : ws[k-256,n]) (into d_out+4MB)
//   grid.sync()
// phase 2 : 64x64 tile GEMM, MFMA frags loaded DIRECTLY from global (L2).
//           No LDS: with register-level a0 x {b0,b1} reuse each 16B chunk is
//           consumed by exactly one thread per block, so LDS staging was pure
//           overhead (round-trip + 16 barriers per block).
//   grid.sync()
// phase 3 : write C (fp32) over d_out.
// ---------------------------------------------------------------------------
__global__ __launch_bounds__(256) void fused_kan(
        const float* __restrict__ x, const float* __restrict__ wb,
        const float* __restrict__ ws, const float* __restrict__ cps,
        const float* __restrict__ knots, float* out) {
    (void)knots;  // uniform knots: closed-form basis, knot values not needed

    short* Abf = (short*)out;                       // [4096][512] bf16 = 4 MB
    short* Btb = Abf + (size_t)BATCH * KDIM;        // [512][512]  bf16 = 0.5 MB

    const int tid = threadIdx.x;
    const int g   = blockIdx.x * 256 + tid;         // 131072 threads total

    // ---- phase 1a: A tile (8 consecutive i per thread, fully coalesced) ----
    {
        const int b  = g >> 5;                      // batch row
        const int i0 = (g & 31) << 3;               // input-dim start
        float xv[8];
        *(f32x4*)&xv[0] = *(const f32x4*)&x[b * IN_DIM + i0];
        *(f32x4*)&xv[4] = *(const f32x4*)&x[b * IN_DIM + i0 + 4];
        bf16x8 sil, spl;
        #pragma unroll
        for (int e = 0; e < 8; ++e) {
            float v = xv[e];
            float s = v / (1.0f + __expf(-v));      // silu
            // uniform cubic B-spline, knots = linspace(-1,1,64), h = 2/63
            float u  = (v + 1.0f) * 31.5f;
            float fj = floorf(u);
            int   j  = (int)fj;
            float sp = 0.0f;
            if (j >= 0 && j <= 62) {
                float t  = u - fj;                  // exact: (v - knots[j])/h
                float t2 = t * t, t3 = t2 * t;
                float omt = 1.0f - t;
                const float c6 = 1.0f / 6.0f;
                float w0 = omt * omt * omt * c6;                       // k0
                float w1 = (3.0f*t3 - 6.0f*t2 + 4.0f) * c6;            // k0+1
                float w2 = (-3.0f*t3 + 3.0f*t2 + 3.0f*t + 1.0f) * c6;  // k0+2
                float w3 = t3 * c6;                                    // k0+3
                const float* cp = cps + (i0 + e) * NKNOTS;
                int k0 = j - 3;
                // reference truncates basis to [0, NBASIS) — mask edges
                if (k0     >= 0 && k0     < NBASIS) sp += w0 * cp[k0];
                if (k0 + 1 >= 0 && k0 + 1 < NBASIS) sp += w1 * cp[k0 + 1];
                if (k0 + 2 >= 0 && k0 + 2 < NBASIS) sp += w2 * cp[k0 + 2];
                if (               k0 + 3 < NBASIS) sp += w3 * cp[k0 + 3]; // k0+3=j>=0
            }
            sil[e] = f2bf(s);
            spl[e] = f2bf(sp);
        }
        *(bf16x8*)&Abf[b * KDIM + i0]          = sil;
        *(bf16x8*)&Abf[b * KDIM + IN_DIM + i0] = spl;
    }

    // ---- phase 1b: Bt (reads coalesced over n; 2 scattered 2B writes) ----
    {
        const int n  = g & 511;
        const int kq = g >> 9;                      // 0..255
        Btb[n * KDIM + kq]          = f2bf(wb[kq * OUT_DIM + n]);
        Btb[n * KDIM + IN_DIM + kq] = f2bf(ws[kq * OUT_DIM + n]);
    }

    cooperative_groups::this_grid().sync();

    // ---- phase 2: GEMM, frags direct from global (L2-resident A/B) ----
    // XCD-bijective swizzle (512 % 8 == 0): each XCD gets 8 consecutive m-rows
    // of blocks x all n -> its L2 holds a 512 KB A-slice + the full 0.5 MB B.
    const int bid  = blockIdx.x;
    const int sbid = (bid & 7) * 64 + (bid >> 3);
    const int n0   = (sbid & 7) * 64;
    const int m0   = (sbid >> 3) * 64;
    const int lane = tid & 63;
    const int wave = tid >> 6;
    const int wm   = (wave & 1) * 32;               // wave's 32x32 quadrant
    const int wn   = (wave >> 1) * 32;
    const int fr   = lane & 15;                     // fragment row/col index
    const int koff = (lane >> 4) * 8;               // k offset within MFMA K=32

    const short* A0 = Abf + (size_t)(m0 + wm + fr) * KDIM + koff;
    const short* A1 = A0 + 16 * KDIM;
    const short* B0 = Btb + (size_t)(n0 + wn + fr) * KDIM + koff;
    const short* B1 = B0 + 16 * KDIM;

    f32x4 acc[2][2] = {};
    #pragma unroll 4
    for (int k = 0; k < KDIM; k += 32) {
        bf16x8 a0 = *(const bf16x8*)(A0 + k);
        bf16x8 a1 = *(const bf16x8*)(A1 + k);
        bf16x8 b0 = *(const bf16x8*)(B0 + k);
        bf16x8 b1 = *(const bf16x8*)(B1 + k);
        acc[0][0] = __builtin_amdgcn_mfma_f32_16x16x32_bf16(a0, b0, acc[0][0], 0, 0, 0);
        acc[0][1] = __builtin_amdgcn_mfma_f32_16x16x32_bf16(a0, b1, acc[0][1], 0, 0, 0);
        acc[1][0] = __builtin_amdgcn_mfma_f32_16x16x32_bf16(a1, b0, acc[1][0], 0, 0, 0);
        acc[1][1] = __builtin_amdgcn_mfma_f32_16x16x32_bf16(a1, b1, acc[1][1], 0, 0, 0);
    }

    cooperative_groups::this_grid().sync();   // all A/Bt reads done everywhere

    // ---- phase 3: C overwrite. layout col=lane&15, row=(lane>>4)*4+reg ----
    const int rbase = (lane >> 4) * 4;
    #pragma unroll
    for (int mt = 0; mt < 2; ++mt) {
        #pragma unroll
        for (int nt = 0; nt < 2; ++nt) {
            #pragma unroll
            for (int r = 0; r < 4; ++r) {
                int row = m0 + wm + mt * 16 + rbase + r;
                int col = n0 + wn + nt * 16 + fr;
                out[row * OUT_DIM + col] = acc[mt][nt][r];
            }
        }
    }
}

// ---------------------------------------------------------------------------
extern "C" void kernel_launch(void* const* d_in, const int* in_sizes, int n_in,
                              void* d_out, int out_size, void* d_ws, size_t ws_size,
                              hipStream_t stream) {
    (void)in_sizes; (void)n_in; (void)d_ws; (void)ws_size; (void)out_size;
    const float* x     = (const float*)d_in[0];
    const float* wb    = (const float*)d_in[1];
    const float* wsp   = (const float*)d_in[2];
    const float* cps   = (const float*)d_in[3];
    const float* knots = (const float*)d_in[4];
    float* out = (float*)d_out;

    void* args[] = {(void*)&x, (void*)&wb, (void*)&wsp, (void*)&cps,
                    (void*)&knots, (void*)&out};
    hipLaunchCooperativeKernel((const void*)fused_kan, dim3(512), dim3(256),
                               args, 0, stream);
}

// Round 2
// 87.781 us; speedup vs baseline: 2.5071x; 2.5071x over previous
//
#include <hip/hip_runtime.h>
#include <hip/hip_bf16.h>

// Problem constants (from reference)
#define BATCH    4096
#define IN_DIM   256
#define OUT_DIM  512
#define KDIM     512       // concat K: [silu(x) | spline(x)]
#define NKNOTS   64
#define NBASIS   60        // NUM_KNOTS - DEGREE - 1

typedef __attribute__((ext_vector_type(8))) short bf16x8;   // 8 bf16 in 4 VGPRs
typedef __attribute__((ext_vector_type(4))) float f32x4;

// Module-scope staging buffers: allocated at module load, NOT the harness
// workspace (using d_ws triggered a timed 256 MB poison-fill ~45 us), and NOT
// d_out (round 1: in-place staging forced cooperative grid syncs ~70 us each).
// Cross-kernel ordering comes free from stream launch order.
__device__ __align__(16) short g_A [BATCH   * KDIM];   // 4 MB bf16
__device__ __align__(16) short g_Bt[OUT_DIM * KDIM];   // 0.5 MB bf16

__device__ __forceinline__ short f2bf(float f) {
    __hip_bfloat16 h = __float2bfloat16(f);
    return *reinterpret_cast<short*>(&h);
}

#define NBLK_A 512   // A-prep blocks (4096*512 bf16, 8+8 elems/thread)
#define NBLK_B 64    // Bt-transpose blocks (64x64 fp32 tiles via LDS)

// ---------------------------------------------------------------------------
// Kernel 1 (prep): blocks [0,512) build A = [silu(x) | spline(x)] in bf16;
// blocks [512,576) build Bt[n][k] = bf16(k<256 ? wb[k][n] : ws[k-256][n])
// via an LDS 64x64 transpose so global reads AND writes are wide/coalesced
// (round 1's 2-byte scattered Bt writes inflated WRITE_SIZE ~5 MB).
// ---------------------------------------------------------------------------
__global__ __launch_bounds__(256) void prep_kernel(
        const float* __restrict__ x, const float* __restrict__ wb,
        const float* __restrict__ ws, const float* __restrict__ cps) {
    __shared__ float T[64][65];   // +1 pad: conflict-free column reads

    if (blockIdx.x < NBLK_A) {
        // ---- A: silu | spline, 8 consecutive i per thread, vectorized ----
        const int g  = blockIdx.x * 256 + threadIdx.x;
        const int b  = g >> 5;                      // batch row
        const int i0 = (g & 31) << 3;               // input-dim start
        float xv[8];
        *(f32x4*)&xv[0] = *(const f32x4*)&x[b * IN_DIM + i0];
        *(f32x4*)&xv[4] = *(const f32x4*)&x[b * IN_DIM + i0 + 4];
        bf16x8 sil, spl;
        #pragma unroll
        for (int e = 0; e < 8; ++e) {
            float v = xv[e];
            float s = v / (1.0f + __expf(-v));      // silu
            // uniform cubic B-spline, knots = linspace(-1,1,64), h = 2/63
            float u  = (v + 1.0f) * 31.5f;
            float fj = floorf(u);
            int   j  = (int)fj;
            float sp = 0.0f;
            if (j >= 0 && j <= 62) {
                float t  = u - fj;                  // exact: (v - knots[j])/h
                float t2 = t * t, t3 = t2 * t;
                float omt = 1.0f - t;
                const float c6 = 1.0f / 6.0f;
                float w0 = omt * omt * omt * c6;                       // k0
                float w1 = (3.0f*t3 - 6.0f*t2 + 4.0f) * c6;            // k0+1
                float w2 = (-3.0f*t3 + 3.0f*t2 + 3.0f*t + 1.0f) * c6;  // k0+2
                float w3 = t3 * c6;                                    // k0+3
                const float* cp = cps + (i0 + e) * NKNOTS;
                int k0 = j - 3;
                // reference truncates basis to [0, NBASIS) — mask edges
                if (k0     >= 0 && k0     < NBASIS) sp += w0 * cp[k0];
                if (k0 + 1 >= 0 && k0 + 1 < NBASIS) sp += w1 * cp[k0 + 1];
                if (k0 + 2 >= 0 && k0 + 2 < NBASIS) sp += w2 * cp[k0 + 2];
                if (               k0 + 3 < NBASIS) sp += w3 * cp[k0 + 3];
            }
            sil[e] = f2bf(s);
            spl[e] = f2bf(sp);
        }
        *(bf16x8*)&g_A[b * KDIM + i0]          = sil;
        *(bf16x8*)&g_A[b * KDIM + IN_DIM + i0] = spl;
    } else {
        // ---- Bt: LDS-transpose one 64(k) x 64(n) fp32 tile ----
        const int bb = blockIdx.x - NBLK_A;         // 0..63
        const int k0 = (bb >> 3) * 64;              // K-tile (concat axis)
        const int n0 = (bb & 7) * 64;               // N-tile
        // 256 % 64 == 0: whole tile comes from one source matrix
        const float* W = (k0 < IN_DIM) ? wb + (size_t)k0 * OUT_DIM
                                       : ws + (size_t)(k0 - IN_DIM) * OUT_DIM;
        const int t  = threadIdx.x;
        const int r  = t >> 2;                      // 0..63
        const int c0 = (t & 3) * 16;                // 16-elem chunk
        #pragma unroll
        for (int e = 0; e < 16; e += 4) {           // 64B contiguous per thread
            f32x4 v = *(const f32x4*)&W[r * OUT_DIM + n0 + c0 + e];
            T[r][c0 + e + 0] = v[0];
            T[r][c0 + e + 1] = v[1];
            T[r][c0 + e + 2] = v[2];
            T[r][c0 + e + 3] = v[3];
        }
        __syncthreads();
        // read transposed column (pad 65 -> bank = (k + n) % 32, conflict-free)
        short tmp[16];
        #pragma unroll
        for (int e = 0; e < 16; ++e) tmp[e] = f2bf(T[c0 + e][r]);
        *(bf16x8*)&g_Bt[(n0 + r) * KDIM + k0 + c0]     = *(bf16x8*)&tmp[0];
        *(bf16x8*)&g_Bt[(n0 + r) * KDIM + k0 + c0 + 8] = *(bf16x8*)&tmp[8];
    }
}

// ---------------------------------------------------------------------------
// Kernel 2: C[4096,512] = A @ Bt^T. 64x64 tile, 4 independent 32x32 waves.
// No LDS, no barriers: within a block each A 16B chunk is consumed by exactly
// one lane, B chunks by two waves (L1-served) — staging adds nothing.
// A (4 MB) + Bt (0.5 MB) are L2-resident; XCD-bijective swizzle gives each
// XCD a contiguous 512 KB A-slice (8 m-tiles x all n) for L2 locality.
// ---------------------------------------------------------------------------
__global__ __launch_bounds__(256) void gemm_kernel(float* __restrict__ C) {
    const int bid  = blockIdx.x;                    // 512 blocks, 512 % 8 == 0
    const int sbid = (bid & 7) * 64 + (bid >> 3);   // bijective XCD swizzle
    const int m0   = (sbid >> 3) * 64;
    const int n0   = (sbid & 7) * 64;
    const int tid  = threadIdx.x;
    const int lane = tid & 63;
    const int wave = tid >> 6;
    const int wm   = (wave & 1) * 32;               // wave's 32x32 quadrant
    const int wn   = (wave >> 1) * 32;
    const int fr   = lane & 15;                     // fragment row/col index
    const int koff = (lane >> 4) * 8;               // k offset within MFMA K=32

    const short* A0 = g_A  + (size_t)(m0 + wm + fr) * KDIM + koff;
    const short* A1 = A0 + 16 * KDIM;
    const short* B0 = g_Bt + (size_t)(n0 + wn + fr) * KDIM + koff;
    const short* B1 = B0 + 16 * KDIM;

    f32x4 acc[2][2] = {};
    #pragma unroll 4
    for (int k = 0; k < KDIM; k += 32) {
        bf16x8 a0 = *(const bf16x8*)(A0 + k);
        bf16x8 a1 = *(const bf16x8*)(A1 + k);
        bf16x8 b0 = *(const bf16x8*)(B0 + k);
        bf16x8 b1 = *(const bf16x8*)(B1 + k);
        acc[0][0] = __builtin_amdgcn_mfma_f32_16x16x32_bf16(a0, b0, acc[0][0], 0, 0, 0);
        acc[0][1] = __builtin_amdgcn_mfma_f32_16x16x32_bf16(a0, b1, acc[0][1], 0, 0, 0);
        acc[1][0] = __builtin_amdgcn_mfma_f32_16x16x32_bf16(a1, b0, acc[1][0], 0, 0, 0);
        acc[1][1] = __builtin_amdgcn_mfma_f32_16x16x32_bf16(a1, b1, acc[1][1], 0, 0, 0);
    }

    // epilogue: C/D layout col = lane&15, row = (lane>>4)*4 + reg  [m89-verified]
    const int rbase = (lane >> 4) * 4;
    #pragma unroll
    for (int mt = 0; mt < 2; ++mt) {
        #pragma unroll
        for (int nt = 0; nt < 2; ++nt) {
            #pragma unroll
            for (int r = 0; r < 4; ++r) {
                int row = m0 + wm + mt * 16 + rbase + r;
                int col = n0 + wn + nt * 16 + fr;
                C[row * OUT_DIM + col] = acc[mt][nt][r];
            }
        }
    }
}

// ---------------------------------------------------------------------------
extern "C" void kernel_launch(void* const* d_in, const int* in_sizes, int n_in,
                              void* d_out, int out_size, void* d_ws, size_t ws_size,
                              hipStream_t stream) {
    (void)in_sizes; (void)n_in; (void)d_ws; (void)ws_size; (void)out_size;
    const float* x   = (const float*)d_in[0];
    const float* wb  = (const float*)d_in[1];
    const float* wsp = (const float*)d_in[2];
    const float* cps = (const float*)d_in[3];
    // d_in[4] = knots: uniform, closed-form basis — values not needed
    float* out = (float*)d_out;

    prep_kernel<<<NBLK_A + NBLK_B, 256, 0, stream>>>(x, wb, wsp, cps);
    gemm_kernel<<<512, 256, 0, stream>>>(out);
}

// Round 3
// 78.039 us; speedup vs baseline: 2.8200x; 1.1248x over previous
//
#include <hip/hip_runtime.h>
#include <hip/hip_bf16.h>

// Problem constants (from reference)
#define BATCH    4096
#define IN_DIM   256
#define OUT_DIM  512
#define KDIM     512       // concat K: [silu(x) | spline(x)]
#define NKNOTS   64
#define NBASIS   60        // NUM_KNOTS - DEGREE - 1

typedef __attribute__((ext_vector_type(8))) short bf16x8;   // 8 bf16 in 4 VGPRs
typedef __attribute__((ext_vector_type(4))) float f32x4;

// Module-scope staging buffers (allocated at load). NOTE (r2 post-mortem):
// the harness poisons d_ws with a 256 MB fill EVERY iteration regardless of
// use (~42 us, unconditional) — so d_ws vs device-globals is perf-neutral;
// globals kept for simplicity. Cross-kernel ordering via stream launch order.
__device__ __align__(16) short g_A [BATCH   * KDIM];   // 4 MB bf16
__device__ __align__(16) short g_Bt[OUT_DIM * KDIM];   // 0.5 MB bf16

__device__ __forceinline__ short f2bf(float f) {
    __hip_bfloat16 h = __float2bfloat16(f);
    return *reinterpret_cast<short*>(&h);
}

#define NBLK_A 512   // A-prep blocks (4096*512 bf16, 8+8 elems/thread)
#define NBLK_B 64    // Bt-transpose blocks (64x64 fp32 tiles via LDS)

// ---------------------------------------------------------------------------
// Kernel 1 (prep): blocks [0,512) build A = [silu(x) | spline(x)] in bf16;
// blocks [512,576) build Bt[n][k] = bf16(k<256 ? wb[k][n] : ws[k-256][n])
// via an LDS 64x64 transpose (wide coalesced reads AND writes).
// ---------------------------------------------------------------------------
__global__ __launch_bounds__(256) void prep_kernel(
        const float* __restrict__ x, const float* __restrict__ wb,
        const float* __restrict__ ws, const float* __restrict__ cps) {
    __shared__ float T[64][65];   // +1 pad: conflict-free column reads

    if (blockIdx.x < NBLK_A) {
        // ---- A: silu | spline, 8 consecutive i per thread, vectorized ----
        const int g  = blockIdx.x * 256 + threadIdx.x;
        const int b  = g >> 5;                      // batch row
        const int i0 = (g & 31) << 3;               // input-dim start
        float xv[8];
        *(f32x4*)&xv[0] = *(const f32x4*)&x[b * IN_DIM + i0];
        *(f32x4*)&xv[4] = *(const f32x4*)&x[b * IN_DIM + i0 + 4];
        bf16x8 sil, spl;
        #pragma unroll
        for (int e = 0; e < 8; ++e) {
            float v = xv[e];
            float s = v / (1.0f + __expf(-v));      // silu
            // uniform cubic B-spline, knots = linspace(-1,1,64), h = 2/63
            float u  = (v + 1.0f) * 31.5f;
            float fj = floorf(u);
            int   j  = (int)fj;
            float sp = 0.0f;
            if (j >= 0 && j <= 62) {
                float t  = u - fj;                  // exact: (v - knots[j])/h
                float t2 = t * t, t3 = t2 * t;
                float omt = 1.0f - t;
                const float c6 = 1.0f / 6.0f;
                float w0 = omt * omt * omt * c6;                       // k0
                float w1 = (3.0f*t3 - 6.0f*t2 + 4.0f) * c6;            // k0+1
                float w2 = (-3.0f*t3 + 3.0f*t2 + 3.0f*t + 1.0f) * c6;  // k0+2
                float w3 = t3 * c6;                                    // k0+3
                const float* cp = cps + (i0 + e) * NKNOTS;
                int k0 = j - 3;
                // reference truncates basis to [0, NBASIS) — mask edges
                if (k0     >= 0 && k0     < NBASIS) sp += w0 * cp[k0];
                if (k0 + 1 >= 0 && k0 + 1 < NBASIS) sp += w1 * cp[k0 + 1];
                if (k0 + 2 >= 0 && k0 + 2 < NBASIS) sp += w2 * cp[k0 + 2];
                if (               k0 + 3 < NBASIS) sp += w3 * cp[k0 + 3];
            }
            sil[e] = f2bf(s);
            spl[e] = f2bf(sp);
        }
        *(bf16x8*)&g_A[b * KDIM + i0]          = sil;
        *(bf16x8*)&g_A[b * KDIM + IN_DIM + i0] = spl;
    } else {
        // ---- Bt: LDS-transpose one 64(k) x 64(n) fp32 tile ----
        const int bb = blockIdx.x - NBLK_A;         // 0..63
        const int k0 = (bb >> 3) * 64;              // K-tile (concat axis)
        const int n0 = (bb & 7) * 64;               // N-tile
        // 256 % 64 == 0: whole tile comes from one source matrix
        const float* W = (k0 < IN_DIM) ? wb + (size_t)k0 * OUT_DIM
                                       : ws + (size_t)(k0 - IN_DIM) * OUT_DIM;
        const int t  = threadIdx.x;
        const int r  = t >> 2;                      // 0..63
        const int c0 = (t & 3) * 16;                // 16-elem chunk
        #pragma unroll
        for (int e = 0; e < 16; e += 4) {           // 64B contiguous per thread
            f32x4 v = *(const f32x4*)&W[r * OUT_DIM + n0 + c0 + e];
            T[r][c0 + e + 0] = v[0];
            T[r][c0 + e + 1] = v[1];
            T[r][c0 + e + 2] = v[2];
            T[r][c0 + e + 3] = v[3];
        }
        __syncthreads();
        // read transposed column (pad 65 -> conflict-free)
        short tmp[16];
        #pragma unroll
        for (int e = 0; e < 16; ++e) tmp[e] = f2bf(T[c0 + e][r]);
        *(bf16x8*)&g_Bt[(n0 + r) * KDIM + k0 + c0]     = *(bf16x8*)&tmp[0];
        *(bf16x8*)&g_Bt[(n0 + r) * KDIM + k0 + c0 + 8] = *(bf16x8*)&tmp[8];
    }
}

// ---------------------------------------------------------------------------
// Kernel 2: C[4096,512] = A @ Bt^T. 64x64 tile, 4 waves of 32x32, BK=128.
// LDS-staged (r2 lesson: at a kernel boundary L2 is cold, so direct-global
// MFMA fragment reads are L3-served ~500cyc with only 2 waves/SIMD to hide
// them — LDS staging amortizes that latency into wide coalesced bursts).
// LDSS=136: row stride 272B, 16B-aligned; paired rows 2-way bank alias = free.
// ---------------------------------------------------------------------------
#define BM 64
#define BN 64
#define BK 128
#define LDSS 136

__global__ __launch_bounds__(256) void gemm_kernel(float* __restrict__ C) {
    __shared__ __align__(16) short As[BM * LDSS];
    __shared__ __align__(16) short Bs[BN * LDSS];

    const int bid  = blockIdx.x;                    // 512 blocks, 512 % 8 == 0
    const int sbid = (bid & 7) * 64 + (bid >> 3);   // bijective XCD swizzle
    const int m0   = (sbid >> 3) * 64;
    const int n0   = (sbid & 7) * 64;
    const int tid  = threadIdx.x;
    const int lane = tid & 63;
    const int wave = tid >> 6;
    const int wm   = (wave & 1) * 32;               // wave's 32x32 quadrant
    const int wn   = (wave >> 1) * 32;
    const int fr   = lane & 15;                     // fragment row/col index
    const int koff = (lane >> 4) * 8;               // k offset within MFMA K=32

    f32x4 acc[2][2] = {};

    for (int k0 = 0; k0 < KDIM; k0 += BK) {
        // stage: tile = 64 rows x 16 chunks(16B) = 1024 chunks; 4/thread each
        #pragma unroll
        for (int s = 0; s < 4; ++s) {
            const int c = tid + s * 256;
            const int r = c >> 4, o = (c & 15) * 8;
            *(uint4*)&As[r * LDSS + o] = *(const uint4*)&g_A [(m0 + r) * KDIM + k0 + o];
            *(uint4*)&Bs[r * LDSS + o] = *(const uint4*)&g_Bt[(n0 + r) * KDIM + k0 + o];
        }
        __syncthreads();

        #pragma unroll
        for (int kk = 0; kk < BK; kk += 32) {
            bf16x8 a0 = *(const bf16x8*)&As[(wm + fr)      * LDSS + kk + koff];
            bf16x8 a1 = *(const bf16x8*)&As[(wm + 16 + fr) * LDSS + kk + koff];
            bf16x8 b0 = *(const bf16x8*)&Bs[(wn + fr)      * LDSS + kk + koff];
            bf16x8 b1 = *(const bf16x8*)&Bs[(wn + 16 + fr) * LDSS + kk + koff];
            acc[0][0] = __builtin_amdgcn_mfma_f32_16x16x32_bf16(a0, b0, acc[0][0], 0, 0, 0);
            acc[0][1] = __builtin_amdgcn_mfma_f32_16x16x32_bf16(a0, b1, acc[0][1], 0, 0, 0);
            acc[1][0] = __builtin_amdgcn_mfma_f32_16x16x32_bf16(a1, b0, acc[1][0], 0, 0, 0);
            acc[1][1] = __builtin_amdgcn_mfma_f32_16x16x32_bf16(a1, b1, acc[1][1], 0, 0, 0);
        }
        __syncthreads();
    }

    // epilogue: C/D layout col = lane&15, row = (lane>>4)*4 + reg  [m89-verified]
    const int rbase = (lane >> 4) * 4;
    #pragma unroll
    for (int mt = 0; mt < 2; ++mt) {
        #pragma unroll
        for (int nt = 0; nt < 2; ++nt) {
            #pragma unroll
            for (int r = 0; r < 4; ++r) {
                int row = m0 + wm + mt * 16 + rbase + r;
                int col = n0 + wn + nt * 16 + fr;
                C[row * OUT_DIM + col] = acc[mt][nt][r];
            }
        }
    }
}

// ---------------------------------------------------------------------------
extern "C" void kernel_launch(void* const* d_in, const int* in_sizes, int n_in,
                              void* d_out, int out_size, void* d_ws, size_t ws_size,
                              hipStream_t stream) {
    (void)in_sizes; (void)n_in; (void)d_ws; (void)ws_size; (void)out_size;
    const float* x   = (const float*)d_in[0];
    const float* wb  = (const float*)d_in[1];
    const float* wsp = (const float*)d_in[2];
    const float* cps = (const float*)d_in[3];
    // d_in[4] = knots: uniform, closed-form basis — values not needed
    float* out = (float*)d_out;

    prep_kernel<<<NBLK_A + NBLK_B, 256, 0, stream>>>(x, wb, wsp, cps);
    gemm_kernel<<<512, 256, 0, stream>>>(out);
}